// Round 4
// baseline (235.087 us; speedup 1.0000x reference)
//
#include <hip/hip_runtime.h>
#include <hip/hip_bf16.h>
#include <math.h>

constexpr int BB = 2;
constexpr int LL = 1024;
constexpr int DD = 768;
constexpr int HH = 12;
constexpr int NEz = 42;
constexpr int MM = 8;
constexpr int NPp = 1722;
constexpr int CC = 97;
constexpr int FF = 256;
constexpr int PAIRS = NEz * NEz;         // 1764
constexpr int TOTAL = BB * NPp;          // 3444

constexpr int MT = 96;                   // rows per k_bil tile
constexpr int NT = 36;                   // ceil(3444/96)
constexpr int OG2 = 7;                   // o's per block
constexpr int NOG = 14;                  // 13*7+6 = 97
constexpr int NWG2 = NT * NOG;           // 504 = 8*63

typedef float f32x4 __attribute__((ext_vector_type(4)));
typedef short bf16x8 __attribute__((ext_vector_type(8)));
typedef unsigned short u16x4 __attribute__((ext_vector_type(4)));

__device__ inline short f2bs(float x) {
    __hip_bfloat16 b = __float2bfloat16(x);
    return *(short*)&b;
}
__device__ inline float bs2f(unsigned short u) {
    return __uint_as_float(((unsigned)u) << 16);
}
__device__ inline void gload16(const void* g, void* l) {
    __builtin_amdgcn_global_load_lds((const __attribute__((address_space(1))) unsigned int*)g,
                                     (__attribute__((address_space(3))) unsigned int*)l, 16, 0, 0);
}

// ---------------- K1: seqW[b,l,k] = sum_d seq[b,l,d] * W_lin[d,k] ----------------
__global__ void k_seqw(const float* __restrict__ seq, const float* __restrict__ Wl,
                       float* __restrict__ seqW) {
    int bl = blockIdx.x;
    int lane = threadIdx.x;
    const float* row = seq + (size_t)bl * DD;
    float a0 = 0.f, a1 = 0.f, a2 = 0.f;
    for (int d = lane; d < DD; d += 64) {
        float v = row[d];
        a0 += v * Wl[d * 3 + 0];
        a1 += v * Wl[d * 3 + 1];
        a2 += v * Wl[d * 3 + 2];
    }
    for (int off = 32; off; off >>= 1) {
        a0 += __shfl_down(a0, off);
        a1 += __shfl_down(a1, off);
        a2 += __shfl_down(a2, off);
    }
    if (lane == 0) {
        seqW[bl * 3 + 0] = a0;
        seqW[bl * 3 + 1] = a1;
        seqW[bl * 3 + 2] = a2;
    }
}

// ---------------- K2: ent_emb = masked logsumexp over M mentions ----------------
__global__ void k_ent_emb(const float* __restrict__ seq, const int* __restrict__ midx,
                          const int* __restrict__ mmask, float* __restrict__ ent_emb) {
    int be = blockIdx.x;
    int b = be / NEz;
    int tid = threadIdx.x;
    int idx[MM], msk[MM];
#pragma unroll
    for (int m = 0; m < MM; ++m) {
        idx[m] = midx[be * MM + m];
        msk[m] = mmask[be * MM + m];
    }
    const float* sb = seq + (size_t)b * LL * DD;
    for (int d = tid; d < DD; d += 256) {
        float v[MM];
        float mx = -1e30f;
#pragma unroll
        for (int m = 0; m < MM; ++m) {
            v[m] = msk[m] ? sb[(size_t)idx[m] * DD + d] : -1e30f;
            mx = fmaxf(mx, v[m]);
        }
        float s = 0.f;
#pragma unroll
        for (int m = 0; m < MM; ++m) s += expf(v[m] - mx);
        ent_emb[(size_t)be * DD + d] = mx + logf(s);
    }
}

// ---------------- K3: ent_att ----------------
__global__ void k_ent_att(const float* __restrict__ att, const int* __restrict__ midx,
                          const int* __restrict__ mmask, float* __restrict__ ea) {
    int beh = blockIdx.x;
    int h = beh % HH;
    int be = beh / HH;
    int b = be / NEz;
    int tid = threadIdx.x;
    int idx[MM], msk[MM];
    float msum = 0.f;
#pragma unroll
    for (int m = 0; m < MM; ++m) {
        idx[m] = midx[be * MM + m];
        msk[m] = mmask[be * MM + m];
        msum += (float)msk[m];
    }
    float inv = 1.f / msum;
    const float* ab = att + ((size_t)b * HH + h) * LL * LL;
#pragma unroll
    for (int li = 0; li < 4; ++li) {
        int l = tid + li * 256;
        float acc = 0.f;
#pragma unroll
        for (int m = 0; m < MM; ++m)
            if (msk[m]) acc += ab[(size_t)idx[m] * LL + l];
        ea[(size_t)beh * LL + l] = acc * inv;
    }
}

// ---------------- K4a: per (b, l-chunk of 8): ht partial sums + projections ------
// partial[b][lcb][pair][4] = {sum_l ht, sum_l ht*sw0, sum_l ht*sw1, sum_l ht*sw2}
__global__ void k_pairAB(const float* __restrict__ ea, const float* __restrict__ seqW,
                         float* __restrict__ szp) {
    int lcb = blockIdx.x;   // 0..127
    int b = blockIdx.y;
    int l0 = lcb * 8;
    int tid = threadIdx.x;  // 384 = 6 waves
    int lane = tid & 63;
    int e1 = (tid >> 6) * 8 + (lane >> 3);
    int l = lane & 7;

    __shared__ float S[NEz][HH][9];
    __shared__ float sw[8][3];

    for (int idx = tid; idx < NEz * HH * 8; idx += 384) {
        int e = idx / 96, rem = idx % 96;
        int h = rem / 8, ll = rem % 8;
        S[e][h][ll] = ea[((size_t)(b * NEz + e) * HH + h) * LL + l0 + ll];
    }
    if (tid < 24) sw[tid / 3][tid % 3] = seqW[((size_t)b * LL + l0 + tid / 3) * 3 + tid % 3];
    __syncthreads();

    bool act = e1 < NEz;
    float e1r[HH];
#pragma unroll
    for (int h = 0; h < HH; ++h) e1r[h] = act ? S[e1][h][l] : 0.f;
    float sw0 = sw[l][0], sw1 = sw[l][1], sw2 = sw[l][2];

    for (int e2 = 0; e2 < NEz; ++e2) {
        float ht = 0.f;
#pragma unroll
        for (int h = 0; h < HH; ++h) ht += e1r[h] * S[e2][h][l];
        ht *= (1.0f / HH);
        float v0 = ht, v1 = ht * sw0, v2 = ht * sw1, v3 = ht * sw2;
#pragma unroll
        for (int off = 1; off < 8; off <<= 1) {
            v0 += __shfl_xor(v0, off);
            v1 += __shfl_xor(v1, off);
            v2 += __shfl_xor(v2, off);
            v3 += __shfl_xor(v3, off);
        }
        if (act && l == 0) {
            float4 o4 = make_float4(v0, v1, v2, v3);
            *(float4*)&szp[((size_t)(b * 128 + lcb) * PAIRS + e1 * NEz + e2) * 4] = o4;
        }
    }
}

// ---------------- K4b: reduce partials -> z -> attn_map row ----------------------
__global__ void k_pairC(const float* __restrict__ szp, const float* __restrict__ Wseg,
                        const float* __restrict__ bseg, const float* __restrict__ blin,
                        float* __restrict__ am) {
    int bp = blockIdx.x;            // b*PAIRS + p
    int b = bp / PAIRS;
    int p = bp % PAIRS;
    int tid = threadIdx.x;          // 256

    __shared__ float zz[3];
    if (tid < 64) {
        float4 a = *(const float4*)&szp[((size_t)(b * 128 + tid) * PAIRS + p) * 4];
        float4 c = *(const float4*)&szp[((size_t)(b * 128 + tid + 64) * PAIRS + p) * 4];
        float v0 = a.x + c.x, v1 = a.y + c.y, v2 = a.z + c.z, v3 = a.w + c.w;
#pragma unroll
        for (int off = 1; off < 64; off <<= 1) {
            v0 += __shfl_xor(v0, off);
            v1 += __shfl_xor(v1, off);
            v2 += __shfl_xor(v2, off);
            v3 += __shfl_xor(v3, off);
        }
        if (tid == 0) {
            float inv = 1.f / (v0 + 1e-5f);
            zz[0] = v1 * inv + blin[0];
            zz[1] = v2 * inv + blin[1];
            zz[2] = v3 * inv + blin[2];
        }
    }
    __syncthreads();
    float val = zz[0] * Wseg[tid] + zz[1] * Wseg[FF + tid] + zz[2] * Wseg[2 * FF + tid] + bseg[tid];
    am[(size_t)bp * FF + tid] = fmaxf(val, 0.f);
}

// ---------------- K5: EWh/EWt = ent_emb @ W_head/tail + bias ---------------------
__global__ void k_ew(const float* __restrict__ ent_emb, const float* __restrict__ Wh,
                     const float* __restrict__ bh, const float* __restrict__ Wt,
                     const float* __restrict__ bt, float* __restrict__ EWh,
                     float* __restrict__ EWt) {
    int be = blockIdx.x;
    int tid = threadIdx.x;
    __shared__ float e[DD];
    for (int d = tid; d < DD; d += 256) e[d] = ent_emb[(size_t)be * DD + d];
    __syncthreads();
    float ah = bh[tid], at = bt[tid];
    for (int d = 0; d < DD; ++d) {
        float ev = e[d];
        ah += ev * Wh[d * FF + tid];
        at += ev * Wt[d * FF + tid];
    }
    EWh[(size_t)be * FF + tid] = ah;
    EWt[(size_t)be * FF + tid] = at;
}

// ---------------- K6a: W_frag: B-fragment-ordered bf16 image of W_bil ------------
// slot(o,kr,wc,ks,ni,lane) holds W[o][k..k+8][n], k=kr*128+ks*32+(lane>>4)*8,
// n=wc*64+ni*16+(lane&15).  16B per slot, contiguous per (o,kr,wc).
__global__ void k_wt(const float* __restrict__ Wb, short* __restrict__ Wf) {
    int o = blockIdx.y;
    int kt = blockIdx.x >> 2, ct = blockIdx.x & 3;
    int tid = threadIdx.x;      // 256
    int lane6 = tid & 63, q = tid >> 6;
    __shared__ float t64[64][65];
    const float* src = Wb + (size_t)o * FF * FF;
#pragma unroll 4
    for (int i = 0; i < 16; ++i) {
        int kk = q * 16 + i;
        t64[kk][lane6] = src[(size_t)(kt * 64 + kk) * FF + ct * 64 + lane6];
    }
    __syncthreads();
    int kr = kt >> 1, wc = ct;
#pragma unroll
    for (int s = 0; s < 2; ++s) {
        int slot = tid + s * 256;           // (ks2*4+ni)*64 + lane
        int ks2 = slot >> 8, ni = (slot >> 6) & 3, ln = slot & 63;
        int kl = ks2 * 32 + (ln >> 4) * 8;
        int nl = ni * 16 + (ln & 15);
        bf16x8 val;
#pragma unroll
        for (int j = 0; j < 8; ++j) val[j] = f2bs(t64[kl + j][nl]);
        int ksg = (kt & 1) * 2 + ks2;
        size_t off = ((((size_t)(o * 2 + kr) * 4 + wc) * 4 + ksg) * 4 + ni) * 64 + ln;
        *(bf16x8*)(Wf + off * 8) = val;
    }
}

// ---------------- K6b: HS A-fragments + TS transposed tiles ----------------------
__global__ void k_prep(const float* __restrict__ EWh, const float* __restrict__ EWt,
                       const float* __restrict__ am, const int* __restrict__ hts,
                       short* __restrict__ HSf, short* __restrict__ TSt) {
    int tile = blockIdx.x;
    int tid = threadIdx.x;   // 512
    // A fragments: slot = ((kr*6+mi)*4+kc)*64 + ln
    for (int s = tid; s < 3072; s += 512) {
        int ln = s & 63, kc = (s >> 6) & 3;
        int mk = s >> 8;
        int mi = mk % 6, kr = mk / 6;
        int p = tile * MT + mi * 16 + (ln & 15);
        int k = kr * 128 + kc * 32 + (ln >> 4) * 8;
        bf16x8 v = {0, 0, 0, 0, 0, 0, 0, 0};
        if (p < TOTAL) {
            int b = p / NPp;
            int e1 = hts[p * 2 + 0], e2 = hts[p * 2 + 1];
            const float* hr = EWh + (size_t)(b * NEz + e1) * FF + k;
            const float* ar = am + ((size_t)b * PAIRS + e1 * NEz + e2) * FF + k;
#pragma unroll
            for (int j = 0; j < 8; ++j) v[j] = f2bs(tanhf(hr[j] + ar[j]));
        }
        size_t off = ((size_t)tile * 48 + kr * 24 + mi * 4 + kc) * 64 + ln;
        *(bf16x8*)(HSf + off * 8) = v;
    }
    // TS transposed: TSt[tile][c][r], r-stride 100
    for (int idx = tid; idx < FF * MT; idx += 512) {
        int c = idx / MT, r = idx % MT;
        int p = tile * MT + r;
        short v = 0;
        if (p < TOTAL) {
            int b = p / NPp;
            int e1 = hts[p * 2 + 0], e2 = hts[p * 2 + 1];
            float a = am[((size_t)b * PAIRS + e1 * NEz + e2) * FF + c];
            v = f2bs(tanhf(EWt[(size_t)(b * NEz + e2) * FF + c] + a));
        }
        TSt[(size_t)tile * 25600 + c * 100 + r] = v;
    }
}

// ---------------- K6c: bilinear via per-wave streamed MFMA -----------------------
// Block: 96 rows x 256 cols x K=256, OG2 o's.  8 waves = (kr 2) x (wc 4);
// wave tile: 96 rows x 64 cols x 128 k.  A in registers, B streamed through a
// private 2x4KB LDS ring via global_load_lds.  No barriers in the main loop.
__launch_bounds__(512, 2)
__global__ void k_bil(const short* __restrict__ HSf, const short* __restrict__ TSt,
                      const short* __restrict__ Wf, const float* __restrict__ bbil,
                      float* __restrict__ out) {
    int f = blockIdx.x;
    int wg = (f & 7) * 63 + (f >> 3);        // 504 = 8*63 exact, bijective
    int og = wg / NT;
    int tile = wg % NT;
    int o0 = og * OG2;
    int nO = (CC - o0 < OG2) ? (CC - o0) : OG2;

    int tid = threadIdx.x;
    int lane = tid & 63, w = tid >> 6;
    int kr = w >> 2, wc = w & 3;
    int lr = lane & 15, lg = lane >> 4;

    __shared__ short TSl[FF * 100];          // 50 KB
    __shared__ float red[OG2][MT][8];        // 21 KB
    __shared__ char Bbuf[8][8192];           // 64 KB

    // stage TS tile (linear copy)
    {
        const unsigned int* ts_src = (const unsigned int*)(TSt + (size_t)tile * 25600);
        unsigned int* ts_dst = (unsigned int*)TSl;
        for (int i = tid; i < 12800; i += 512) ts_dst[i] = ts_src[i];
    }

    // A fragments in registers (96 VGPR), this wave's K-half
    bf16x8 af[6][4];
    {
        const short* ab = HSf + ((size_t)tile * 48 + kr * 24) * 512;
#pragma unroll
        for (int mi = 0; mi < 6; ++mi)
#pragma unroll
            for (int kc = 0; kc < 4; ++kc)
                af[mi][kc] = *(const bf16x8*)(ab + ((mi * 4 + kc) * 64 + lane) * 8);
    }

    char* Bw = &Bbuf[w][0];
    const char* Wfb = (const char*)Wf + (size_t)(kr * 4 + wc) * 16384;

    // prologue: stage chunk 0
    {
        const char* s = Wfb + (size_t)o0 * 131072;
#pragma unroll
        for (int fi = 0; fi < 4; ++fi)
            gload16(s + fi * 1024 + lane * 16, Bw + fi * 1024 + lane * 16);
    }
    __syncthreads();   // TS ready (also drains chunk-0 stage)

    for (int oi = 0; oi < nO; ++oi) {
        f32x4 acc[6][4];
#pragma unroll
        for (int mi = 0; mi < 6; ++mi)
#pragma unroll
            for (int ni = 0; ni < 4; ++ni) acc[mi][ni] = (f32x4){0.f, 0.f, 0.f, 0.f};

#pragma unroll
        for (int kc = 0; kc < 4; ++kc) {
            asm volatile("s_waitcnt vmcnt(0)" ::: "memory");
            __builtin_amdgcn_sched_barrier(0);
            bf16x8 bfr[4];
#pragma unroll
            for (int ni = 0; ni < 4; ++ni)
                bfr[ni] = *(const bf16x8*)(Bw + (kc & 1) * 4096 + ni * 1024 + lane * 16);
            __builtin_amdgcn_sched_barrier(0);
            // stage next chunk into the other half of the ring
            {
                int cc1 = oi * 4 + kc + 1;
                if (cc1 < nO * 4) {
                    const char* s = Wfb + (size_t)(o0 + (cc1 >> 2)) * 131072 + (cc1 & 3) * 4096;
                    char* d = Bw + ((kc + 1) & 1) * 4096;
#pragma unroll
                    for (int fi = 0; fi < 4; ++fi)
                        gload16(s + fi * 1024 + lane * 16, d + fi * 1024 + lane * 16);
                }
            }
            __builtin_amdgcn_sched_barrier(0);
            __builtin_amdgcn_s_setprio(1);
#pragma unroll
            for (int ni = 0; ni < 4; ++ni)
#pragma unroll
                for (int mi = 0; mi < 6; ++mi)
                    acc[mi][ni] = __builtin_amdgcn_mfma_f32_16x16x32_bf16(
                        af[mi][kc], bfr[ni], acc[mi][ni], 0, 0, 0);
            __builtin_amdgcn_s_setprio(0);
        }

        // epilogue: dot with TS, reduce over the 16 lr lanes
#pragma unroll
        for (int mi = 0; mi < 6; ++mi) {
            int rb = mi * 16 + lg * 4;
            float sum[4] = {0.f, 0.f, 0.f, 0.f};
#pragma unroll
            for (int ni = 0; ni < 4; ++ni) {
                int c = wc * 64 + ni * 16 + lr;
                u16x4 ts4 = *(const u16x4*)(TSl + c * 100 + rb);
#pragma unroll
                for (int reg = 0; reg < 4; ++reg)
                    sum[reg] += acc[mi][ni][reg] * bs2f(ts4[reg]);
            }
#pragma unroll
            for (int reg = 0; reg < 4; ++reg) {
                float v = sum[reg];
                v += __shfl_xor(v, 1);
                v += __shfl_xor(v, 2);
                v += __shfl_xor(v, 4);
                v += __shfl_xor(v, 8);
                if (lr == 0) red[oi][rb + reg][w] = v;
            }
        }
    }

    __syncthreads();
    for (int t = tid; t < nO * MT; t += 512) {
        int oi = t / MT, r = t % MT;
        int p = tile * MT + r;
        if (p < TOTAL) {
            float s = red[oi][r][0] + red[oi][r][1] + red[oi][r][2] + red[oi][r][3] +
                      red[oi][r][4] + red[oi][r][5] + red[oi][r][6] + red[oi][r][7];
            out[(size_t)p * CC + o0 + oi] = s + bbil[o0 + oi];
        }
    }
}

extern "C" void kernel_launch(void* const* d_in, const int* in_sizes, int n_in,
                              void* d_out, int out_size, void* d_ws, size_t ws_size,
                              hipStream_t stream) {
    const float* seq   = (const float*)d_in[0];
    const float* att   = (const float*)d_in[1];
    const int*   midx  = (const int*)d_in[2];
    const int*   mmask = (const int*)d_in[3];
    const int*   hts   = (const int*)d_in[4];
    const float* Wlin  = (const float*)d_in[5];
    const float* blin  = (const float*)d_in[6];
    const float* Wseg  = (const float*)d_in[7];
    const float* bseg  = (const float*)d_in[8];
    const float* Whead = (const float*)d_in[9];
    const float* bhead = (const float*)d_in[10];
    const float* Wtail = (const float*)d_in[11];
    const float* btail = (const float*)d_in[12];
    const float* Wbil  = (const float*)d_in[13];
    const float* bbil  = (const float*)d_in[14];
    float* out = (float*)d_out;

    float* ws = (float*)d_ws;
    float* ent_emb = ws;                                     // 64512
    float* ea      = ent_emb + BB * NEz * DD;                // 1032192
    float* seqW    = ea + (size_t)BB * NEz * HH * LL;        // 6144
    float* EWh     = seqW + BB * LL * 3;                     // 21504
    float* EWt     = EWh + BB * NEz * FF;                    // 21504
    float* am      = EWt + BB * NEz * FF;                    // 903168
    float* szp     = am + (size_t)BB * PAIRS * FF;           // 2*128*1764*4
    short* Wf      = (short*)(szp + (size_t)BB * 128 * PAIRS * 4);   // 97*65536 sh
    short* HSf     = Wf + (size_t)CC * FF * FF;                      // 36*24576 sh
    short* TSt     = HSf + (size_t)NT * MT * FF;                     // 36*25600 sh

    k_seqw<<<BB * LL, 64, 0, stream>>>(seq, Wlin, seqW);
    k_ent_emb<<<BB * NEz, 256, 0, stream>>>(seq, midx, mmask, ent_emb);
    k_ent_att<<<BB * NEz * HH, 256, 0, stream>>>(att, midx, mmask, ea);
    k_pairAB<<<dim3(128, BB), 384, 0, stream>>>(ea, seqW, szp);
    k_pairC<<<BB * PAIRS, 256, 0, stream>>>(szp, Wseg, bseg, blin, am);
    k_ew<<<BB * NEz, 256, 0, stream>>>(ent_emb, Whead, bhead, Wtail, btail, EWh, EWt);
    k_wt<<<dim3(16, CC), 256, 0, stream>>>(Wbil, Wf);
    k_prep<<<NT, 512, 0, stream>>>(EWh, EWt, am, hts, HSf, TSt);
    k_bil<<<NWG2, 512, 0, stream>>>(HSf, TSt, Wf, bbil, out);
}